// Round 9
// baseline (156.341 us; speedup 1.0000x reference)
//
#include <hip/hip_runtime.h>
#include <hip/hip_cooperative_groups.h>

namespace cg = cooperative_groups;

// B=8, N=128, COOR=3, F=128, FILT=128
#define BB   8
#define NN   128
#define FF   128
#define KK   128

typedef float f32x4 __attribute__((ext_vector_type(4)));

// ---------------------------------------------------------------------------
// Fused cooperative kernel. Grid 1024 x 256 (4 blocks/CU -> easy co-residency).
// Phase 1: block bx computes AC row bn=bx: [A+bias/2 (128) | C+bias/2 (128)]
//          per coor. vf row staged in LDS; w reads coalesced.
// grid.sync()
// Phase 2: R4/R5 k_main body: 4i x 32j tile, dist tile in LDS, A row in
//          registers, C rows from L2, NT float4 stores (best-known from R8 A/B).
// ---------------------------------------------------------------------------
__global__ __launch_bounds__(256, 4) void k_fused(const float* __restrict__ vf,
                                                  const float* __restrict__ dist,
                                                  const float* __restrict__ w,
                                                  const float* __restrict__ bias,
                                                  float* __restrict__ ac,
                                                  float* __restrict__ out) {
    cg::grid_group grid = cg::this_grid();
    const int bx  = blockIdx.x;
    const int tid = threadIdx.x;
    __shared__ float sh[768];   // phase1: vf row (384 used); phase2: dist tile (384)

    // ---- Phase 1: AC[bx][c][half*128+col] ----
    if (tid < 96) {
        ((float4*)sh)[tid] = ((const float4*)(vf + (size_t)bx * 384))[tid];
    }
    __syncthreads();

    {
        const int col  = tid & 127;
        const int half = tid >> 7;                 // 0 = A-half, 1 = C-half
        const float* wcol = w + half * (FF * KK) + col;
        float a0 = 0.f, a1 = 0.f, a2 = 0.f;
#pragma unroll 16
        for (int f = 0; f < FF; ++f) {
            const float wv = wcol[f * KK];
            a0 = fmaf(wv, sh[f],       a0);
            a1 = fmaf(wv, sh[128 + f], a1);
            a2 = fmaf(wv, sh[256 + f], a2);
        }
        const float hb = 0.5f * bias[col];
        float* dst = ac + (size_t)bx * 768 + half * 128 + col;
        dst[0]   = a0 + hb;
        dst[256] = a1 + hb;
        dst[512] = a2 + hb;
    }

    grid.sync();

    // ---- Phase 2: out tile (b, i0..i0+3, j0..j0+31, :) ----
    const int b   = bx >> 7;            // 128 blocks per batch
    const int rem = bx & 127;
    const int it  = rem >> 2;           // 0..31
    const int jt  = rem & 3;            // 0..3 (low bits -> XCD affinity on C)
    const int i0  = it * 4, j0 = jt * 32;

    for (int idx = tid; idx < 384; idx += 256) {
        const int ti = idx / 96, r = idx % 96;
        sh[idx] = dist[((size_t)(b * NN + i0 + ti) * NN + j0) * 3 + r];
    }
    __syncthreads();

    const int k4  = tid & 31;
    const int rg  = tid >> 5;
    const int ti  = rg & 3;
    const int rg4 = rg >> 2;
    const int i   = i0 + ti;

    const float4* arow = (const float4*)(ac + (size_t)(b * NN + i) * 768) + k4;
    const float4 a0 = arow[0], a1 = arow[64], a2 = arow[128];
    float* obase = out + (size_t)(b * NN + i) * NN * KK;
    const float* dlt = sh + ti * 96;

#pragma unroll 4
    for (int p = 0; p < 16; ++p) {
        const int jj = 2 * p + rg4;
        const int j  = j0 + jj;
        const float d0 = dlt[jj * 3], d1 = dlt[jj * 3 + 1], d2 = dlt[jj * 3 + 2];

        const float4* crow = (const float4*)(ac + (size_t)(b * NN + j) * 768)
                             + 32 + k4;          // +128 floats: C-half
        const float4 c0 = crow[0], c1 = crow[64], c2 = crow[128];

        f32x4 r;
        r.x = fmaf(d0, a0.x + c0.x, fmaf(d1, a1.x + c1.x, d2 * (a2.x + c2.x)));
        r.y = fmaf(d0, a0.y + c0.y, fmaf(d1, a1.y + c1.y, d2 * (a2.y + c2.y)));
        r.z = fmaf(d0, a0.z + c0.z, fmaf(d1, a1.z + c1.z, d2 * (a2.z + c2.z)));
        r.w = fmaf(d0, a0.w + c0.w, fmaf(d1, a1.w + c1.w, d2 * (a2.w + c2.w)));

        __builtin_nontemporal_store(r, (f32x4*)(obase + (size_t)j * KK + k4 * 4));
    }
}

// ---------------------------------------------------------------------------
// Fallback two-kernel path (R5 exact) if cooperative launch is unavailable.
// ---------------------------------------------------------------------------
__global__ __launch_bounds__(256) void k_pre(const float* __restrict__ vf,
                                             const float* __restrict__ w,
                                             const float* __restrict__ bias,
                                             float* __restrict__ ac) {
    const int bn0 = blockIdx.x * 2;
    const int tid = threadIdx.x;
    __shared__ float vfr[768];
    if (tid < 192) {
        ((float4*)vfr)[tid] = ((const float4*)(vf + (size_t)bn0 * 384))[tid];
    }
    __syncthreads();

    const int col  = tid & 127;
    const int half = tid >> 7;
    const float* wcol = w + half * (FF * KK) + col;

    float a00 = 0.f, a01 = 0.f, a02 = 0.f;
    float a10 = 0.f, a11 = 0.f, a12 = 0.f;
#pragma unroll 16
    for (int f = 0; f < FF; ++f) {
        const float wv = wcol[f * KK];
        a00 = fmaf(wv, vfr[f],       a00);
        a01 = fmaf(wv, vfr[128 + f], a01);
        a02 = fmaf(wv, vfr[256 + f], a02);
        a10 = fmaf(wv, vfr[384 + f], a10);
        a11 = fmaf(wv, vfr[512 + f], a11);
        a12 = fmaf(wv, vfr[640 + f], a12);
    }
    const float hb = 0.5f * bias[col];
    float* dst = ac + (size_t)bn0 * 768 + half * 128 + col;
    dst[0]    = a00 + hb;  dst[256]  = a01 + hb;  dst[512]  = a02 + hb;
    dst[768]  = a10 + hb;  dst[1024] = a11 + hb;  dst[1280] = a12 + hb;
}

__global__ __launch_bounds__(256) void k_main(const float* __restrict__ dist,
                                              const float* __restrict__ ac,
                                              float* __restrict__ out) {
    const int bx  = blockIdx.x;
    const int b   = bx >> 8;
    const int rem = bx & 255;
    const int it  = rem >> 3;
    const int jt  = rem & 7;
    const int i0  = it * 4, j0 = jt * 16;
    const int tid = threadIdx.x;

    __shared__ float dl[192];
    if (tid < 192) {
        const int ti = tid / 48, r = tid % 48;
        dl[tid] = dist[((size_t)(b * NN + i0 + ti) * NN + j0) * 3 + r];
    }
    __syncthreads();

    const int k4  = tid & 31;
    const int rg  = tid >> 5;
    const int ti  = rg & 3;
    const int rg4 = rg >> 2;
    const int i   = i0 + ti;

    const float4* arow = (const float4*)(ac + (size_t)(b * NN + i) * 768) + k4;
    const float4 a0 = arow[0], a1 = arow[64], a2 = arow[128];
    float* obase = out + (size_t)(b * NN + i) * NN * KK;
    const float* dlt = dl + ti * 48;

#pragma unroll
    for (int p = 0; p < 8; ++p) {
        const int jj = 2 * p + rg4;
        const int j  = j0 + jj;
        const float d0 = dlt[jj * 3], d1 = dlt[jj * 3 + 1], d2 = dlt[jj * 3 + 2];

        const float4* crow = (const float4*)(ac + (size_t)(b * NN + j) * 768)
                             + 32 + k4;
        const float4 c0 = crow[0], c1 = crow[64], c2 = crow[128];

        f32x4 r;
        r.x = fmaf(d0, a0.x + c0.x, fmaf(d1, a1.x + c1.x, d2 * (a2.x + c2.x)));
        r.y = fmaf(d0, a0.y + c0.y, fmaf(d1, a1.y + c1.y, d2 * (a2.y + c2.y)));
        r.z = fmaf(d0, a0.z + c0.z, fmaf(d1, a1.z + c1.z, d2 * (a2.z + c2.z)));
        r.w = fmaf(d0, a0.w + c0.w, fmaf(d1, a1.w + c1.w, d2 * (a2.w + c2.w)));

        __builtin_nontemporal_store(r, (f32x4*)(obase + (size_t)j * KK + k4 * 4));
    }
}

// Slow fallback (ws too small): fused recompute. Correct but slow.
__global__ __launch_bounds__(256) void k_fused_slow(const float* __restrict__ vf,
                                                    const float* __restrict__ dist,
                                                    const float* __restrict__ w,
                                                    const float* __restrict__ bias,
                                                    float* __restrict__ out) {
    const int bi  = blockIdx.x;
    const int b   = bi >> 7;
    const int tid = threadIdx.x;
    __shared__ float arow[384];
    __shared__ float crow[384];

    for (int idx = tid; idx < 384; idx += 256) {
        const int c = idx >> 7, k = idx & 127;
        const float* v = vf + (size_t)bi * 384 + c * 128;
        float s = 0.f;
        for (int f = 0; f < 128; ++f) s = fmaf(v[f], w[f * 128 + k], s);
        arow[idx] = s;
    }
    __syncthreads();

    for (int j = 0; j < NN; ++j) {
        for (int idx = tid; idx < 384; idx += 256) {
            const int c = idx >> 7, k = idx & 127;
            const float* v = vf + (size_t)(b * NN + j) * 384 + c * 128;
            float s = 0.f;
            for (int f = 0; f < 128; ++f) s = fmaf(v[f], w[(128 + f) * 128 + k], s);
            crow[idx] = s;
        }
        __syncthreads();
        if (tid < 128) {
            const float* dj = dist + ((size_t)bi * NN + j) * 3;
            const float d0 = dj[0], d1 = dj[1], d2 = dj[2];
            const float sd = d0 + d1 + d2;
            const float r = fmaf(d0, arow[tid] + crow[tid],
                            fmaf(d1, arow[128 + tid] + crow[128 + tid],
                            fmaf(d2, arow[256 + tid] + crow[256 + tid], sd * bias[tid])));
            out[((size_t)bi * NN + j) * 128 + tid] = r;
        }
        __syncthreads();
    }
}

extern "C" void kernel_launch(void* const* d_in, const int* in_sizes, int n_in,
                              void* d_out, int out_size, void* d_ws, size_t ws_size,
                              hipStream_t stream) {
    const float* vf   = (const float*)d_in[0];   // [8,128,3,128]
    const float* dist = (const float*)d_in[1];   // [8,128,128,3]
    const float* w    = (const float*)d_in[2];   // [256,128]
    const float* bias = (const float*)d_in[3];   // [128]
    float* out = (float*)d_out;                  // [8,128,128,128]

    const size_t need = (size_t)BB * NN * 3 * 256 * sizeof(float);  // 3 MB
    if (ws_size < need) {
        k_fused_slow<<<BB * NN, 256, 0, stream>>>(vf, dist, w, bias, out);
        return;
    }
    float* ac = (float*)d_ws;

    void* args[] = {(void*)&vf, (void*)&dist, (void*)&w, (void*)&bias,
                    (void*)&ac, (void*)&out};
    hipError_t e = hipLaunchCooperativeKernel((const void*)k_fused,
                                              dim3(1024), dim3(256),
                                              args, 0, stream);
    if (e != hipSuccess) {
        // Fallback: two-kernel R5 path.
        k_pre<<<512, 256, 0, stream>>>(vf, w, bias, ac);
        k_main<<<2048, 256, 0, stream>>>(dist, ac, out);
    }
}

// Round 10
// 26.542 us; speedup vs baseline: 5.8903x; 5.8903x over previous
//
#include <hip/hip_runtime.h>

// B=8, N=128, COOR=3, F=128, FILT=128
#define BB   8
#define NN   128
#define FF   128
#define KK   128

typedef float f32x4 __attribute__((ext_vector_type(4)));

// ---------------------------------------------------------------------------
// Kernel 1: AC[bn][c][2x128]: per (bn,c): [A+bias/2 (128) | C+bias/2 (128)]
//   A[bn,c,k] = sum_f vf[bn,c,f] * w[f,k],  C uses w[128+f,k].
// vs R5: NO LDS — vf reads are thread-uniform (depend only on blockIdx) so
// they scalarize to s_load (SMEM pipe, free); removes 6 ds_read_b32 per
// f-iter (~3.7 us of LDS-pipe serialization at 2 waves/SIMD). w loads
// unchanged (coalesced, L2-resident). Grid 512, 2 rows/block.
// ---------------------------------------------------------------------------
__global__ __launch_bounds__(256) void k_pre(const float* __restrict__ vf,
                                             const float* __restrict__ w,
                                             const float* __restrict__ bias,
                                             float* __restrict__ ac) {
    const int bn0 = blockIdx.x * 2;
    const int tid = threadIdx.x;
    const int col  = tid & 127;
    const int half = tid >> 7;                     // 0 = A-half, 1 = C-half
    const float* wcol = w + half * (FF * KK) + col;
    const float* vr = vf + (size_t)bn0 * 384;      // uniform -> s_load

    float a00 = 0.f, a01 = 0.f, a02 = 0.f;
    float a10 = 0.f, a11 = 0.f, a12 = 0.f;
#pragma unroll 8
    for (int f = 0; f < FF; ++f) {
        const float wv = wcol[f * KK];
        a00 = fmaf(wv, vr[f],       a00);
        a01 = fmaf(wv, vr[128 + f], a01);
        a02 = fmaf(wv, vr[256 + f], a02);
        a10 = fmaf(wv, vr[384 + f], a10);
        a11 = fmaf(wv, vr[512 + f], a11);
        a12 = fmaf(wv, vr[640 + f], a12);
    }
    const float hb = 0.5f * bias[col];
    float* dst = ac + (size_t)bn0 * 768 + half * 128 + col;
    dst[0]    = a00 + hb;  dst[256]  = a01 + hb;  dst[512]  = a02 + hb;
    dst[768]  = a10 + hb;  dst[1024] = a11 + hb;  dst[1280] = a12 + hb;
}

// ---------------------------------------------------------------------------
// Kernel 2: out[b,i,j,k] = sum_c d[b,i,j,c] * (A'[b,i,c,k] + C'[b,j,c,k])
// R5 structure (grid 2048: 4i x 16j tiles, dist-LDS, full unroll, NT stores).
// ONE change: lane remap ti = rg>>1 (wave-uniform i), jp = rg&1 -> each wave's
// 64 lanes write TWO CONSECUTIVE j-rows at one i = one contiguous 1 KB
// segment per store instruction (was 2 x 512 B segments 64 KB apart).
// ---------------------------------------------------------------------------
__global__ __launch_bounds__(256) void k_main(const float* __restrict__ dist,
                                              const float* __restrict__ ac,
                                              float* __restrict__ out) {
    const int bx  = blockIdx.x;
    const int b   = bx >> 8;            // 256 blocks per batch
    const int rem = bx & 255;
    const int it  = rem >> 3;           // 0..31
    const int jt  = rem & 7;            // 0..7 (low bits -> XCD affinity on C)
    const int i0  = it * 4, j0 = jt * 16;
    const int tid = threadIdx.x;

    __shared__ float dl[192];           // [ti][jj][c] = 4 x 16 x 3
    if (tid < 192) {
        const int ti = tid / 48, r = tid % 48;
        dl[tid] = dist[((size_t)(b * NN + i0 + ti) * NN + j0) * 3 + r];
    }
    __syncthreads();

    const int k4 = tid & 31;
    const int rg = tid >> 5;            // 0..7
    const int ti = rg >> 1;             // 0..3, constant per WAVE
    const int jp = rg & 1;              // j parity within wave
    const int i  = i0 + ti;

    const float4* arow = (const float4*)(ac + (size_t)(b * NN + i) * 768) + k4;
    const float4 a0 = arow[0], a1 = arow[64], a2 = arow[128];
    float* obase = out + (size_t)(b * NN + i) * NN * KK;
    const float* dlt = dl + ti * 48;

#pragma unroll
    for (int p = 0; p < 8; ++p) {
        const int jj = 2 * p + jp;
        const int j  = j0 + jj;
        const float d0 = dlt[jj * 3], d1 = dlt[jj * 3 + 1], d2 = dlt[jj * 3 + 2];

        const float4* crow = (const float4*)(ac + (size_t)(b * NN + j) * 768)
                             + 32 + k4;          // +128 floats: C-half
        const float4 c0 = crow[0], c1 = crow[64], c2 = crow[128];

        f32x4 r;
        r.x = fmaf(d0, a0.x + c0.x, fmaf(d1, a1.x + c1.x, d2 * (a2.x + c2.x)));
        r.y = fmaf(d0, a0.y + c0.y, fmaf(d1, a1.y + c1.y, d2 * (a2.y + c2.y)));
        r.z = fmaf(d0, a0.z + c0.z, fmaf(d1, a1.z + c1.z, d2 * (a2.z + c2.z)));
        r.w = fmaf(d0, a0.w + c0.w, fmaf(d1, a1.w + c1.w, d2 * (a2.w + c2.w)));

        __builtin_nontemporal_store(r, (f32x4*)(obase + (size_t)j * KK + k4 * 4));
    }
}

// ---------------------------------------------------------------------------
// Fallback (only if ws_size < 3 MB): fused, recomputes C per j. Slow but correct.
// ---------------------------------------------------------------------------
__global__ __launch_bounds__(256) void k_fused_slow(const float* __restrict__ vf,
                                                    const float* __restrict__ dist,
                                                    const float* __restrict__ w,
                                                    const float* __restrict__ bias,
                                                    float* __restrict__ out) {
    const int bi  = blockIdx.x;           // b*NN + i
    const int b   = bi >> 7;
    const int tid = threadIdx.x;
    __shared__ float arow[384];
    __shared__ float crow[384];

    for (int idx = tid; idx < 384; idx += 256) {
        const int c = idx >> 7, k = idx & 127;
        const float* v = vf + (size_t)bi * 384 + c * 128;
        float s = 0.f;
        for (int f = 0; f < 128; ++f) s = fmaf(v[f], w[f * 128 + k], s);
        arow[idx] = s;
    }
    __syncthreads();

    for (int j = 0; j < NN; ++j) {
        for (int idx = tid; idx < 384; idx += 256) {
            const int c = idx >> 7, k = idx & 127;
            const float* v = vf + (size_t)(b * NN + j) * 384 + c * 128;
            float s = 0.f;
            for (int f = 0; f < 128; ++f) s = fmaf(v[f], w[(128 + f) * 128 + k], s);
            crow[idx] = s;
        }
        __syncthreads();
        if (tid < 128) {
            const float* dj = dist + ((size_t)bi * NN + j) * 3;
            const float d0 = dj[0], d1 = dj[1], d2 = dj[2];
            const float sd = d0 + d1 + d2;
            const float r = fmaf(d0, arow[tid] + crow[tid],
                            fmaf(d1, arow[128 + tid] + crow[128 + tid],
                            fmaf(d2, arow[256 + tid] + crow[256 + tid], sd * bias[tid])));
            out[((size_t)bi * NN + j) * 128 + tid] = r;
        }
        __syncthreads();
    }
}

extern "C" void kernel_launch(void* const* d_in, const int* in_sizes, int n_in,
                              void* d_out, int out_size, void* d_ws, size_t ws_size,
                              hipStream_t stream) {
    const float* vf   = (const float*)d_in[0];   // [8,128,3,128]
    const float* dist = (const float*)d_in[1];   // [8,128,128,3]
    const float* w    = (const float*)d_in[2];   // [256,128]
    const float* bias = (const float*)d_in[3];   // [128]
    float* out = (float*)d_out;                  // [8,128,128,128]

    const size_t need = (size_t)BB * NN * 3 * 256 * sizeof(float);  // 3 MB
    if (ws_size >= need) {
        float* ac = (float*)d_ws;
        k_pre<<<512, 256, 0, stream>>>(vf, w, bias, ac);
        k_main<<<2048, 256, 0, stream>>>(dist, ac, out);
    } else {
        k_fused_slow<<<BB * NN, 256, 0, stream>>>(vf, dist, w, bias, out);
    }
}